// Round 17
// baseline (220.581 us; speedup 1.0000x reference)
//
#include <hip/hip_runtime.h>
#include <math.h>

typedef unsigned short u16;
typedef __attribute__((ext_vector_type(8))) short bf16x8;
typedef __attribute__((ext_vector_type(4))) short s16x4;
typedef __attribute__((ext_vector_type(4))) float f32x4;

__device__ __forceinline__ u16 f2bf(float f) {
  union { float f; unsigned u; } v; v.f = f;
  unsigned r = v.u + 0x7FFFu + ((v.u >> 16) & 1u);   // RNE
  return (u16)(r >> 16);
}
__device__ __forceinline__ float bf2f(u16 h) {
  union { unsigned u; float f; } v; v.u = ((unsigned)h) << 16; return v.f;
}
__device__ __forceinline__ void gload_lds16(const void* g, void* l) {
  __builtin_amdgcn_global_load_lds((const __attribute__((address_space(1))) void*)g,
                                   (__attribute__((address_space(3))) void*)l, 16, 0, 0);
}
__device__ __forceinline__ float4 ntload4(const float* p) {
  f32x4 v = __builtin_nontemporal_load((const f32x4*)p);   // ext_vector type: valid operand
  return make_float4(v[0], v[1], v[2], v[3]);
}

// ---------------- merged: weight cvt (blocks 0..3071) + adaLN scale/shift (3072..4095) ----------------
__global__ __launch_bounds__(256) void k_pre(
    const float* __restrict__ wq, const float* __restrict__ wk,
    const float* __restrict__ wv, const float* __restrict__ wo,
    const float* __restrict__ w1, const float* __restrict__ w2,
    u16* __restrict__ qkvw, u16* __restrict__ wo_bf,
    u16* __restrict__ w1_bf, u16* __restrict__ w2_bf,
    const float* __restrict__ tc,
    const float* __restrict__ wa, const float* __restrict__ ba,
    const float* __restrict__ wb, const float* __restrict__ bb,
    float* __restrict__ ss1, float* __restrict__ ss2) {
  if (blockIdx.x < 3072) {
    int i = (blockIdx.x * 256 + threadIdx.x) * 4;   // element index, total 3145728
    const float* s; u16* d;
    if (i < 786432) {
      d = qkvw + i;
      if (i < 262144) s = wq + i;
      else if (i < 524288) s = wk + (i - 262144);
      else s = wv + (i - 524288);
    } else if (i < 1048576) { s = wo + (i - 786432); d = wo_bf + (i - 786432); }
    else if (i < 2097152)   { s = w1 + (i - 1048576); d = w1_bf + (i - 1048576); }
    else                    { s = w2 + (i - 2097152); d = w2_bf + (i - 2097152); }
    float4 v = *(const float4*)s;
    s16x4 o;
    o[0] = (short)f2bf(v.x); o[1] = (short)f2bf(v.y);
    o[2] = (short)f2bf(v.z); o[3] = (short)f2bf(v.w);
    *(s16x4*)d = o;
  } else {
    int wv_ = (blockIdx.x - 3072) * 4 + (threadIdx.x >> 6);   // 0..4095
    int l = threadIdx.x & 63;
    int which = wv_ >> 11;
    int rem = wv_ & 2047;
    int b = rem >> 10;
    int row = rem & 1023;
    const float* w = which ? wb : wa;
    const float4* t4 = (const float4*)(tc + b * 512);
    const float4* w4 = (const float4*)(w + (size_t)row * 512);
    float s = 0.f;
#pragma unroll
    for (int q = 0; q < 2; ++q) {
      float4 a = t4[l * 2 + q], c = w4[l * 2 + q];
      s += a.x * c.x + a.y * c.y + a.z * c.z + a.w * c.w;
    }
#pragma unroll
    for (int m = 32; m; m >>= 1) s += __shfl_xor(s, m);
    if (l == 0) {
      float bias = (which ? bb : ba)[row];
      (which ? ss2 : ss1)[b * 1024 + row] = s + bias;
    }
  }
}

// ---------------- adaLN: out = (LN(x)*g+b)*(1+scale)+shift -> bf16 ----------------
__global__ __launch_bounds__(256) void k_adaln(const float* __restrict__ x,
    const float* __restrict__ g, const float* __restrict__ be,
    const float* __restrict__ ss, u16* __restrict__ out) {
  int r = blockIdx.x * 4 + (threadIdx.x >> 6);    // row 0..2047
  int l = threadIdx.x & 63;
  int b = r >> 10;
  const float4* x4 = (const float4*)(x + (size_t)r * 512);
  float4 v0 = x4[l * 2], v1 = x4[l * 2 + 1];
  float s = v0.x + v0.y + v0.z + v0.w + v1.x + v1.y + v1.z + v1.w;
  float s2 = v0.x*v0.x + v0.y*v0.y + v0.z*v0.z + v0.w*v0.w
           + v1.x*v1.x + v1.y*v1.y + v1.z*v1.z + v1.w*v1.w;
#pragma unroll
  for (int m = 32; m; m >>= 1) { s += __shfl_xor(s, m); s2 += __shfl_xor(s2, m); }
  float mu = s * (1.f / 512.f);
  float var = s2 * (1.f / 512.f) - mu * mu;
  float rstd = rsqrtf(var + 1e-5f);
  int c = l * 8;
  float4 g0 = *(const float4*)(g + c),  g1 = *(const float4*)(g + c + 4);
  float4 e0 = *(const float4*)(be + c), e1 = *(const float4*)(be + c + 4);
  const float* sb = ss + b * 1024;
  float4 sc0 = *(const float4*)(sb + c),       sc1 = *(const float4*)(sb + c + 4);
  float4 sh0 = *(const float4*)(sb + 512 + c), sh1 = *(const float4*)(sb + 512 + c + 4);
  float xe[8] = {v0.x,v0.y,v0.z,v0.w,v1.x,v1.y,v1.z,v1.w};
  float gg[8] = {g0.x,g0.y,g0.z,g0.w,g1.x,g1.y,g1.z,g1.w};
  float ee[8] = {e0.x,e0.y,e0.z,e0.w,e1.x,e1.y,e1.z,e1.w};
  float sc[8] = {sc0.x,sc0.y,sc0.z,sc0.w,sc1.x,sc1.y,sc1.z,sc1.w};
  float sh[8] = {sh0.x,sh0.y,sh0.z,sh0.w,sh1.x,sh1.y,sh1.z,sh1.w};
  bf16x8 o;
#pragma unroll
  for (int e = 0; e < 8; ++e) {
    float hv = (xe[e] - mu) * rstd * gg[e] + ee[e];
    float res = hv * (1.f + sc[e]) + sh[e];
    o[e] = (short)f2bf(res);
  }
  *(bf16x8*)(out + (size_t)r * 512 + c) = o;
}

// ---------------- bf16 MFMA GEMM body: C[M,N] = A[M,K] @ Bw[N,K]^T, BMxBN tile ----------------
// LDS XOR-pre-swizzled via global source (global_load_lds dest linear); reads same XOR.
// MODE 0: bf16 out, scale cols<512 by qscale. MODE 1: f32 out = acc+cb+add_.
// MODE 2: bf16 out = gelu(acc+cb). MODE 3: like MODE 1, but A is TWO bf16 flash partials
//   (A and A+1048576) merged with per-(row,head) (m,l) from mlb during reg-staged A-load.
template<int MODE, int BM, int BN>
__device__ __forceinline__ void gemm_body(
    int bxn, int bxm,
    const u16* __restrict__ A, const u16* __restrict__ Bw,
    int M, int N, int K,
    u16* __restrict__ obf, float* __restrict__ of,
    const float* __restrict__ cb, const float* __restrict__ add_,
    float qscale, const float* __restrict__ mlb) {
  constexpr int FM = BM / 32, FN = BN / 32;
  constexpr int WM = BM / 2,  WN = BN / 2;
  __shared__ u16 la[BM * 64];
  __shared__ u16 lb[BN * 64];
  const int tid = threadIdx.x;
  const int l = tid & 63, w = tid >> 6;
  const int wr = w >> 1, wc = w & 1;
  const int m0 = bxm * BM, n0 = bxn * BN;
  f32x4 acc[FM][FN];
  const f32x4 fz = {0.f, 0.f, 0.f, 0.f};
#pragma unroll
  for (int m = 0; m < FM; ++m)
#pragma unroll
    for (int n = 0; n < FN; ++n) acc[m][n] = fz;
  const int nkt = K >> 6;
  for (int kt = 0; kt < nkt; ++kt) {
    const int k0 = kt * 64;
    __syncthreads();
#pragma unroll
    for (int r2 = 0; r2 < BM / 32; ++r2) {
      unsigned e = r2 * 256 + tid;
      unsigned row = e >> 3, ch = (e & 7) ^ (row & 7);
      if (MODE == 3) {
        // merge two bf16 flash partials -> normalized bf16 A chunk -> ds_write (same layout)
        int grow = m0 + (int)row;
        int kbase = k0 + (int)ch * 8;
        int h = kbase >> 5;
        const u16* p0 = A + (size_t)grow * 512 + kbase;
        const u16* p1 = A + 1048576 + (size_t)grow * 512 + kbase;
        s16x4 q00 = *(const s16x4*)p0, q01 = *(const s16x4*)(p0 + 4);
        s16x4 q10 = *(const s16x4*)p1, q11 = *(const s16x4*)(p1 + 4);
        const float2* mlp = (const float2*)mlb;
        float2 ma = mlp[(size_t)grow * 16 + h];
        float2 mc = mlp[32768 + (size_t)grow * 16 + h];
        float mx = fmaxf(ma.x, mc.x);
        float w0 = __expf(ma.x - mx), w1 = __expf(mc.x - mx);
        float inv = 1.f / (ma.y * w0 + mc.y * w1);
        bf16x8 ov;
#pragma unroll
        for (int j = 0; j < 4; ++j) {
          ov[j]     = (short)f2bf((bf2f((u16)q00[j]) * w0 + bf2f((u16)q10[j]) * w1) * inv);
          ov[j + 4] = (short)f2bf((bf2f((u16)q01[j]) * w0 + bf2f((u16)q11[j]) * w1) * inv);
        }
        *(bf16x8*)(la + e * 8) = ov;
      } else {
        gload_lds16(A + (size_t)(m0 + row) * K + k0 + ch * 8, la + (e & ~63u) * 8);
      }
    }
#pragma unroll
    for (int r2 = 0; r2 < BN / 32; ++r2) {
      unsigned e = r2 * 256 + tid;
      unsigned row = e >> 3, ch = (e & 7) ^ (row & 7);
      gload_lds16(Bw + (size_t)(n0 + row) * K + k0 + ch * 8, lb + (e & ~63u) * 8);
    }
    __syncthreads();
#pragma unroll
    for (int kk = 0; kk < 2; ++kk) {
      bf16x8 af[FM], bfr[FN];
#pragma unroll
      for (int m = 0; m < FM; ++m) {
        int R = wr * WM + m * 16 + (l & 15);
        int ch = (kk * 4 + (l >> 4)) ^ (R & 7);
        af[m] = *(const bf16x8*)(la + R * 64 + ch * 8);
      }
#pragma unroll
      for (int n = 0; n < FN; ++n) {
        int R = wc * WN + n * 16 + (l & 15);
        int ch = (kk * 4 + (l >> 4)) ^ (R & 7);
        bfr[n] = *(const bf16x8*)(lb + R * 64 + ch * 8);
      }
#pragma unroll
      for (int m = 0; m < FM; ++m)
#pragma unroll
        for (int n = 0; n < FN; ++n)
          acc[m][n] = __builtin_amdgcn_mfma_f32_16x16x32_bf16(af[m], bfr[n], acc[m][n], 0, 0, 0);
    }
  }
  const int rb  = m0 + wr * WM + ((l >> 4) * 4);
  const int cb0 = n0 + wc * WN + (l & 15);
#pragma unroll
  for (int m = 0; m < FM; ++m)
#pragma unroll
    for (int n = 0; n < FN; ++n) {
      int gcol = cb0 + n * 16;
#pragma unroll
      for (int j = 0; j < 4; ++j) {
        int grow = rb + m * 16 + j;
        float v = acc[m][n][j];
        if (MODE == 0) {
          float scv = (gcol < 512) ? qscale : 1.f;
          obf[(size_t)grow * N + gcol] = f2bf(v * scv);
        } else if (MODE == 1 || MODE == 3) {
          of[(size_t)grow * N + gcol] = v + cb[gcol] + add_[(size_t)grow * N + gcol];
        } else {
          float t = v + cb[gcol];
          float ge = 0.5f * t * (1.f + erff(t * 0.70710678118654752f));
          obf[(size_t)grow * N + gcol] = f2bf(ge);
        }
      }
    }
}

template<int MODE, int BM, int BN>
__global__ __launch_bounds__(256) void k_gemm(
    const u16* __restrict__ A, const u16* __restrict__ Bw,
    int M, int N, int K,
    u16* __restrict__ obf, float* __restrict__ of,
    const float* __restrict__ cb, const float* __restrict__ add_,
    float qscale, const float* __restrict__ mlb) {
  gemm_body<MODE, BM, BN>(blockIdx.x, blockIdx.y, A, Bw, M, N, K, obf, of, cb, add_,
                          qscale, mlb);
}

// ---------------- fused pair-bias + flash attention, j-split x2 + r11 prefetch schedule ----------------
// Block = (i-tile 16, b, j-half); grid (64, 2, 2); 8 waves. Math identical to r15-passing.
// Non-temporal pair loads (streamed once -> don't thrash L2/L3 that K/V reuse),
// non-temporal opart stores, pl single-buffered per wave (in-wave lgkmcnt ordering suffices).
__global__ __launch_bounds__(512, 2) void k_fab3(const u16* __restrict__ qkv,
    const float* __restrict__ pair, const float* __restrict__ wp,
    u16* __restrict__ opart, float* __restrict__ ml) {
  __shared__ u16 vt[8][64 * 64];     // per-wave V^T [d 64][j 64], swizzled (64 KB)
  __shared__ u16 bt[16][16 * 68];    // bias [h][i*68 + j] (34 KB)
  __shared__ u16 pl[8][16 * 64];     // per-wave P (16 KB; reused across heads, in-wave ordered)
  const int tid = threadIdx.x, l = tid & 63, w = tid >> 6;
  const int g = l >> 4, ln = l & 15;
  const int i0 = blockIdx.x * 16;
  const int b  = blockIdx.y;
  const int q  = blockIdx.z;
  const int jt0 = q * 8;
  const u16* base = qkv + (size_t)b * 1024 * 1536;
  const f32x4 fz = {0.f, 0.f, 0.f, 0.f};
  // wp B-frags (n = h = ln, k = c = kk*32 + g*8 + e)
  bf16x8 wf[2];
#pragma unroll
  for (int kk = 0; kk < 2; ++kk) {
    const float* wb = wp + ln * 64 + kk * 32 + g * 8;
    float4 w0 = *(const float4*)(wb);
    float4 w1 = *(const float4*)(wb + 4);
    bf16x8 bb;
    bb[0] = (short)f2bf(w0.x); bb[1] = (short)f2bf(w0.y);
    bb[2] = (short)f2bf(w0.z); bb[3] = (short)f2bf(w0.w);
    bb[4] = (short)f2bf(w1.x); bb[5] = (short)f2bf(w1.y);
    bb[6] = (short)f2bf(w1.z); bb[7] = (short)f2bf(w1.w);
    wf[kk] = bb;
  }
  // Q B-frags: lane ln <-> its own row i0+ln (q pre-scaled in QKV GEMM)
  bf16x8 qb[2];
#pragma unroll
  for (int hh = 0; hh < 2; ++hh)
    qb[hh] = *(const bf16x8*)(base + (size_t)(i0 + ln) * 1536 + (w * 2 + hh) * 32 + g * 8);
  float mr[2] = {-1e30f, -1e30f}, ls[2] = {0.f, 0.f};
  f32x4 oa[2][2];
  oa[0][0] = fz; oa[0][1] = fz; oa[1][0] = fz; oa[1][1] = fz;

  auto PF = [&](float4 (&pf)[4][2][2], int ii, int jj0) {
    const float* prow = pair + ((size_t)(b * 1024 + i0 + w * 2 + ii) * 1024 + jj0) * 64;
#pragma unroll
    for (int jf = 0; jf < 4; ++jf)
#pragma unroll
      for (int kk = 0; kk < 2; ++kk) {
        const float* pp = prow + (jf * 16 + ln) * 64 + kk * 32 + g * 8;
        pf[jf][kk][0] = ntload4(pp);
        pf[jf][kk][1] = ntload4(pp + 4);
      }
  };
  auto CONSUME = [&](float4 (&pf)[4][2][2], int ii) {
#pragma unroll
    for (int jf = 0; jf < 4; ++jf) {
      f32x4 ab = fz;
#pragma unroll
      for (int kk = 0; kk < 2; ++kk) {
        float4 p0 = pf[jf][kk][0], p1 = pf[jf][kk][1];
        bf16x8 pk;
        pk[0] = (short)f2bf(p0.x); pk[1] = (short)f2bf(p0.y);
        pk[2] = (short)f2bf(p0.z); pk[3] = (short)f2bf(p0.w);
        pk[4] = (short)f2bf(p1.x); pk[5] = (short)f2bf(p1.y);
        pk[6] = (short)f2bf(p1.z); pk[7] = (short)f2bf(p1.w);
        ab = __builtin_amdgcn_mfma_f32_16x16x32_bf16(pk, wf[kk], ab, 0, 0, 0);
      }
      s16x4 ov;
      ov[0] = (short)f2bf(ab[0]); ov[1] = (short)f2bf(ab[1]);
      ov[2] = (short)f2bf(ab[2]); ov[3] = (short)f2bf(ab[3]);
      *(s16x4*)(&bt[ln][(w * 2 + ii) * 68 + jf * 16 + g * 4]) = ov;
    }
  };

  float4 pfA[4][2][2], pfB[4][2][2];
  PF(pfA, 0, jt0 * 64);                      // prologue: first tile's ii=0
  for (int jt = jt0; jt < jt0 + 8; ++jt) {
    const int j0 = jt * 64;
    __syncthreads();   // all waves done reading bt/vt of previous tile
    PF(pfB, 1, j0);                          // issue ii=1 while consuming ii=0
    // ---- V-row loads issued EARLY (latency drains under both CONSUMEs) ----
    bf16x8 vv[8];
    {
      const u16* vrow = base + (size_t)(j0 + l) * 1536 + 1024 + w * 64;
#pragma unroll
      for (int qd = 0; qd < 8; ++qd) vv[qd] = *(const bf16x8*)(vrow + qd * 8);
    }
    CONSUME(pfA, 0);
    CONSUME(pfB, 1);
    if (jt + 1 < jt0 + 8) PF(pfA, 0, j0 + 64);   // next tile's ii=0 in flight thru phase B
    // ---- ka K-frag loads (L2) hoisted above the vt transpose writes ----
    bf16x8 ka[2][4];
#pragma unroll
    for (int hh = 0; hh < 2; ++hh)
#pragma unroll
      for (int jf = 0; jf < 4; ++jf)
        ka[hh][jf] = *(const bf16x8*)(base + (size_t)(j0 + jf * 16 + ln) * 1536 + 512 +
                                      (w * 2 + hh) * 32 + g * 8);
    // ---- V^T stage (wave's 2 heads = dims w*64..+63), rows j0+l ----
#pragma unroll
    for (int qd = 0; qd < 8; ++qd)
#pragma unroll
      for (int e = 0; e < 8; ++e) {
        int d = qd * 8 + e;
        vt[w][d * 64 + (l ^ ((d & 7) << 3))] = (u16)vv[qd][e];
      }
    __syncthreads();   // bt (cross-wave) + vt visible
    // ---- phase B: per-head flash step (identical math to r15-passing) ----
#pragma unroll
    for (int hh = 0; hh < 2; ++hh) {
      const int h = w * 2 + hh;
      f32x4 s[4];
#pragma unroll
      for (int jf = 0; jf < 4; ++jf)
        s[jf] = __builtin_amdgcn_mfma_f32_16x16x32_bf16(ka[hh][jf], qb[hh], fz, 0, 0, 0);
#pragma unroll
      for (int jf = 0; jf < 4; ++jf) {
        s16x4 bv = *(const s16x4*)(&bt[h][ln * 68 + jf * 16 + g * 4]);
        s[jf][0] += bf2f((u16)bv[0]);
        s[jf][1] += bf2f((u16)bv[1]);
        s[jf][2] += bf2f((u16)bv[2]);
        s[jf][3] += bf2f((u16)bv[3]);
      }
      float rm = s[0][0];
#pragma unroll
      for (int jf = 0; jf < 4; ++jf)
#pragma unroll
        for (int r = 0; r < 4; ++r) rm = fmaxf(rm, s[jf][r]);
      rm = fmaxf(rm, __shfl_xor(rm, 16));
      rm = fmaxf(rm, __shfl_xor(rm, 32));
      float mn = fmaxf(mr[hh], rm);
      float corr = __expf(mr[hh] - mn);
      float p[4][4];
      float rs = 0.f;
#pragma unroll
      for (int jf = 0; jf < 4; ++jf)
#pragma unroll
        for (int r = 0; r < 4; ++r) { p[jf][r] = __expf(s[jf][r] - mn); rs += p[jf][r]; }
      rs += __shfl_xor(rs, 16);
      rs += __shfl_xor(rs, 32);
      ls[hh] = ls[hh] * corr + rs;
      mr[hh] = mn;
      u16* plw = &pl[w][0];
#pragma unroll
      for (int jf = 0; jf < 4; ++jf) {
        s16x4 pv;
        pv[0] = (short)f2bf(p[jf][0]); pv[1] = (short)f2bf(p[jf][1]);
        pv[2] = (short)f2bf(p[jf][2]); pv[3] = (short)f2bf(p[jf][3]);
        *(s16x4*)(plw + ln * 64 + ((jf * 16 + g * 4) ^ ((ln & 7) << 3))) = pv;
      }
      float cr[4];
#pragma unroll
      for (int r = 0; r < 4; ++r) cr[r] = __shfl(corr, g * 4 + r, 16);
#pragma unroll
      for (int nf = 0; nf < 2; ++nf) {
        oa[hh][nf][0] *= cr[0]; oa[hh][nf][1] *= cr[1];
        oa[hh][nf][2] *= cr[2]; oa[hh][nf][3] *= cr[3];
      }
#pragma unroll
      for (int kk = 0; kk < 2; ++kk) {
        bf16x8 pa = *(const bf16x8*)(plw + ln * 64 + ((kk * 32 + g * 8) ^ ((ln & 7) << 3)));
#pragma unroll
        for (int nf = 0; nf < 2; ++nf) {
          int dp = hh * 32 + nf * 16 + ln;
          bf16x8 vb = *(const bf16x8*)(&vt[w][dp * 64 + ((kk * 32 + g * 8) ^ ((dp & 7) << 3))]);
          oa[hh][nf] = __builtin_amdgcn_mfma_f32_16x16x32_bf16(pa, vb, oa[hh][nf], 0, 0, 0);
        }
      }
    }
  }
  // ---- epilogue: UNNORMALIZED O (bf16, non-temporal) + per-row (m,l); WO MODE 3 merges ----
  u16* op = opart + (size_t)q * 1048576;
#pragma unroll
  for (int hh = 0; hh < 2; ++hh) {
    const int h = w * 2 + hh;
    if (g == 0) {
      float2* mlp = (float2*)ml;
      mlp[(size_t)q * 32768 + (size_t)(b * 1024 + i0 + ln) * 16 + h] =
          make_float2(mr[hh], ls[hh]);
    }
#pragma unroll
    for (int nf = 0; nf < 2; ++nf)
#pragma unroll
      for (int r = 0; r < 4; ++r) {
        int m = g * 4 + r;
        __builtin_nontemporal_store(f2bf(oa[hh][nf][r]),
            op + (size_t)(b * 1024 + i0 + m) * 512 + h * 32 + nf * 16 + ln);
      }
  }
}

extern "C" void kernel_launch(void* const* d_in, const int* in_sizes, int n_in,
                              void* d_out, int out_size, void* d_ws, size_t ws_size,
                              hipStream_t stream) {
  const float* x    = (const float*)d_in[0];
  const float* pair = (const float*)d_in[1];
  const float* tc   = (const float*)d_in[2];
  const float* ln1g = (const float*)d_in[3];
  const float* ln1b = (const float*)d_in[4];
  const float* a1w  = (const float*)d_in[5];
  const float* a1b  = (const float*)d_in[6];
  const float* wq   = (const float*)d_in[7];
  const float* wk   = (const float*)d_in[8];
  const float* wv   = (const float*)d_in[9];
  const float* wp   = (const float*)d_in[10];
  const float* wo   = (const float*)d_in[11];
  const float* bo   = (const float*)d_in[12];
  const float* ln2g = (const float*)d_in[13];
  const float* ln2b = (const float*)d_in[14];
  const float* a2w  = (const float*)d_in[15];
  const float* a2b  = (const float*)d_in[16];
  const float* w1   = (const float*)d_in[17];
  const float* b1   = (const float*)d_in[18];
  const float* w2   = (const float*)d_in[19];
  const float* b2   = (const float*)d_in[20];
  float* out = (float*)d_out;

  char* ws = (char*)d_ws;
  size_t off = 0;
  auto alloc = [&](size_t bytes) {
    size_t cur = off;
    off += (bytes + 255) & ~(size_t)255;
    return (void*)(ws + cur);
  };
  float* ss1    = (float*)alloc(2 * 1024 * 4);
  float* ss2    = (float*)alloc(2 * 1024 * 4);
  u16*   qkvw   = (u16*)alloc((size_t)1536 * 512 * 2);
  u16*   wo_bf  = (u16*)alloc((size_t)512 * 512 * 2);
  u16*   w1_bf  = (u16*)alloc((size_t)2048 * 512 * 2);
  u16*   w2_bf  = (u16*)alloc((size_t)512 * 2048 * 2);
  u16*   h_bf   = (u16*)alloc((size_t)2048 * 512 * 2);
  u16*   qkv_bf = (u16*)alloc((size_t)2048 * 1536 * 2);
  u16*   h2_bf  = (u16*)alloc((size_t)2048 * 512 * 2);
  float* xmid   = (float*)alloc((size_t)2048 * 512 * 4);
  u16*   mid_bf = (u16*)alloc((size_t)2048 * 2048 * 2);
  u16*   opart  = (u16*)alloc((size_t)2 * 2048 * 512 * 2);
  float* mlbuf  = (float*)alloc((size_t)2 * 2048 * 16 * 8);
  (void)ws_size; (void)in_sizes; (void)n_in; (void)out_size;

  // weights -> bf16 + adaLN scale/shift, one launch
  k_pre<<<4096, 256, 0, stream>>>(wq, wk, wv, wo, w1, w2,
                                  qkvw, wo_bf, w1_bf, w2_bf,
                                  tc, a1w, a1b, a2w, a2b, ss1, ss2);

  // adaLN1 -> h (bf16)
  k_adaln<<<512, 256, 0, stream>>>(x, ln1g, ln1b, ss1, h_bf);

  // fused QKV GEMM (q pre-scaled by 1/sqrt(32)); 64x128 tiles, 384 blocks
  k_gemm<0, 64, 128><<<dim3(12, 32), 256, 0, stream>>>(h_bf, qkvw, 2048, 1536, 512,
      qkv_bf, nullptr, nullptr, nullptr, 0.17677669529663687f, nullptr);

  // fused pair-bias + flash attention, j-split x2 (pair read once, bias never hits HBM)
  k_fab3<<<dim3(64, 2, 2), 512, 0, stream>>>(qkv_bf, pair, wp, opart, mlbuf);

  // out proj + residual with FUSED flash-partial merge (MODE 3): xmid = x + merge(opart)@wo^T + bo
  k_gemm<3, 64, 64><<<dim3(8, 32), 256, 0, stream>>>(opart, wo_bf, 2048, 512, 512,
      nullptr, xmid, bo, x, 1.f, mlbuf);

  // adaLN2 -> h2 (bf16)
  k_adaln<<<512, 256, 0, stream>>>(xmid, ln2g, ln2b, ss2, h2_bf);

  // FFN1 + exact GELU -> mid (bf16); 64x128 tiles
  k_gemm<2, 64, 128><<<dim3(16, 32), 256, 0, stream>>>(h2_bf, w1_bf, 2048, 2048, 512,
      mid_bf, nullptr, b1, nullptr, 1.f, nullptr);

  // FFN2 + residual -> out (f32); 64x64 tiles
  k_gemm<1, 64, 64><<<dim3(8, 32), 256, 0, stream>>>(mid_bf, w2_bf, 2048, 512, 2048,
      nullptr, out, b2, xmid, 1.f, nullptr);
}

// Round 18
// 217.390 us; speedup vs baseline: 1.0147x; 1.0147x over previous
//
#include <hip/hip_runtime.h>
#include <math.h>

typedef unsigned short u16;
typedef __attribute__((ext_vector_type(8))) short bf16x8;
typedef __attribute__((ext_vector_type(4))) short s16x4;
typedef __attribute__((ext_vector_type(4))) float f32x4;

__device__ __forceinline__ u16 f2bf(float f) {
  union { float f; unsigned u; } v; v.f = f;
  unsigned r = v.u + 0x7FFFu + ((v.u >> 16) & 1u);   // RNE
  return (u16)(r >> 16);
}
__device__ __forceinline__ float bf2f(u16 h) {
  union { unsigned u; float f; } v; v.u = ((unsigned)h) << 16; return v.f;
}
__device__ __forceinline__ void gload_lds16(const void* g, void* l) {
  __builtin_amdgcn_global_load_lds((const __attribute__((address_space(1))) void*)g,
                                   (__attribute__((address_space(3))) void*)l, 16, 0, 0);
}

// ---------------- merged: weight cvt (blocks 0..3071) + adaLN scale/shift (3072..4095) ----------------
__global__ __launch_bounds__(256) void k_pre(
    const float* __restrict__ wq, const float* __restrict__ wk,
    const float* __restrict__ wv, const float* __restrict__ wo,
    const float* __restrict__ w1, const float* __restrict__ w2,
    u16* __restrict__ qkvw, u16* __restrict__ wo_bf,
    u16* __restrict__ w1_bf, u16* __restrict__ w2_bf,
    const float* __restrict__ tc,
    const float* __restrict__ wa, const float* __restrict__ ba,
    const float* __restrict__ wb, const float* __restrict__ bb,
    float* __restrict__ ss1, float* __restrict__ ss2) {
  if (blockIdx.x < 3072) {
    int i = (blockIdx.x * 256 + threadIdx.x) * 4;   // element index, total 3145728
    const float* s; u16* d;
    if (i < 786432) {
      d = qkvw + i;
      if (i < 262144) s = wq + i;
      else if (i < 524288) s = wk + (i - 262144);
      else s = wv + (i - 524288);
    } else if (i < 1048576) { s = wo + (i - 786432); d = wo_bf + (i - 786432); }
    else if (i < 2097152)   { s = w1 + (i - 1048576); d = w1_bf + (i - 1048576); }
    else                    { s = w2 + (i - 2097152); d = w2_bf + (i - 2097152); }
    float4 v = *(const float4*)s;
    s16x4 o;
    o[0] = (short)f2bf(v.x); o[1] = (short)f2bf(v.y);
    o[2] = (short)f2bf(v.z); o[3] = (short)f2bf(v.w);
    *(s16x4*)d = o;
  } else {
    int wv_ = (blockIdx.x - 3072) * 4 + (threadIdx.x >> 6);   // 0..4095
    int l = threadIdx.x & 63;
    int which = wv_ >> 11;
    int rem = wv_ & 2047;
    int b = rem >> 10;
    int row = rem & 1023;
    const float* w = which ? wb : wa;
    const float4* t4 = (const float4*)(tc + b * 512);
    const float4* w4 = (const float4*)(w + (size_t)row * 512);
    float s = 0.f;
#pragma unroll
    for (int q = 0; q < 2; ++q) {
      float4 a = t4[l * 2 + q], c = w4[l * 2 + q];
      s += a.x * c.x + a.y * c.y + a.z * c.z + a.w * c.w;
    }
#pragma unroll
    for (int m = 32; m; m >>= 1) s += __shfl_xor(s, m);
    if (l == 0) {
      float bias = (which ? bb : ba)[row];
      (which ? ss2 : ss1)[b * 1024 + row] = s + bias;
    }
  }
}

// ---------------- adaLN: out = (LN(x)*g+b)*(1+scale)+shift -> bf16 ----------------
__global__ __launch_bounds__(256) void k_adaln(const float* __restrict__ x,
    const float* __restrict__ g, const float* __restrict__ be,
    const float* __restrict__ ss, u16* __restrict__ out) {
  int r = blockIdx.x * 4 + (threadIdx.x >> 6);    // row 0..2047
  int l = threadIdx.x & 63;
  int b = r >> 10;
  const float4* x4 = (const float4*)(x + (size_t)r * 512);
  float4 v0 = x4[l * 2], v1 = x4[l * 2 + 1];
  float s = v0.x + v0.y + v0.z + v0.w + v1.x + v1.y + v1.z + v1.w;
  float s2 = v0.x*v0.x + v0.y*v0.y + v0.z*v0.z + v0.w*v0.w
           + v1.x*v1.x + v1.y*v1.y + v1.z*v1.z + v1.w*v1.w;
#pragma unroll
  for (int m = 32; m; m >>= 1) { s += __shfl_xor(s, m); s2 += __shfl_xor(s2, m); }
  float mu = s * (1.f / 512.f);
  float var = s2 * (1.f / 512.f) - mu * mu;
  float rstd = rsqrtf(var + 1e-5f);
  int c = l * 8;
  float4 g0 = *(const float4*)(g + c),  g1 = *(const float4*)(g + c + 4);
  float4 e0 = *(const float4*)(be + c), e1 = *(const float4*)(be + c + 4);
  const float* sb = ss + b * 1024;
  float4 sc0 = *(const float4*)(sb + c),       sc1 = *(const float4*)(sb + c + 4);
  float4 sh0 = *(const float4*)(sb + 512 + c), sh1 = *(const float4*)(sb + 512 + c + 4);
  float xe[8] = {v0.x,v0.y,v0.z,v0.w,v1.x,v1.y,v1.z,v1.w};
  float gg[8] = {g0.x,g0.y,g0.z,g0.w,g1.x,g1.y,g1.z,g1.w};
  float ee[8] = {e0.x,e0.y,e0.z,e0.w,e1.x,e1.y,e1.z,e1.w};
  float sc[8] = {sc0.x,sc0.y,sc0.z,sc0.w,sc1.x,sc1.y,sc1.z,sc1.w};
  float sh[8] = {sh0.x,sh0.y,sh0.z,sh0.w,sh1.x,sh1.y,sh1.z,sh1.w};
  bf16x8 o;
#pragma unroll
  for (int e = 0; e < 8; ++e) {
    float hv = (xe[e] - mu) * rstd * gg[e] + ee[e];
    float res = hv * (1.f + sc[e]) + sh[e];
    o[e] = (short)f2bf(res);
  }
  *(bf16x8*)(out + (size_t)r * 512 + c) = o;
}

// ---------------- bf16 MFMA GEMM body: C[M,N] = A[M,K] @ Bw[N,K]^T, BMxBN tile ----------------
// LDS XOR-pre-swizzled via global source (global_load_lds dest linear); reads same XOR.
// MODE 0: bf16 out, scale cols<512 by qscale. MODE 1: f32 out = acc+cb+add_.
// MODE 2: bf16 out = gelu(acc+cb). MODE 3: like MODE 1, but A is TWO bf16 flash partials
//   (A and A+1048576) merged with per-(row,head) (m,l) from mlb during reg-staged A-load.
template<int MODE, int BM, int BN>
__device__ __forceinline__ void gemm_body(
    int bxn, int bxm,
    const u16* __restrict__ A, const u16* __restrict__ Bw,
    int M, int N, int K,
    u16* __restrict__ obf, float* __restrict__ of,
    const float* __restrict__ cb, const float* __restrict__ add_,
    float qscale, const float* __restrict__ mlb) {
  constexpr int FM = BM / 32, FN = BN / 32;
  constexpr int WM = BM / 2,  WN = BN / 2;
  __shared__ u16 la[BM * 64];
  __shared__ u16 lb[BN * 64];
  const int tid = threadIdx.x;
  const int l = tid & 63, w = tid >> 6;
  const int wr = w >> 1, wc = w & 1;
  const int m0 = bxm * BM, n0 = bxn * BN;
  f32x4 acc[FM][FN];
  const f32x4 fz = {0.f, 0.f, 0.f, 0.f};
#pragma unroll
  for (int m = 0; m < FM; ++m)
#pragma unroll
    for (int n = 0; n < FN; ++n) acc[m][n] = fz;
  const int nkt = K >> 6;
  for (int kt = 0; kt < nkt; ++kt) {
    const int k0 = kt * 64;
    __syncthreads();
#pragma unroll
    for (int r2 = 0; r2 < BM / 32; ++r2) {
      unsigned e = r2 * 256 + tid;
      unsigned row = e >> 3, ch = (e & 7) ^ (row & 7);
      if (MODE == 3) {
        // merge two bf16 flash partials -> normalized bf16 A chunk -> ds_write (same layout)
        int grow = m0 + (int)row;
        int kbase = k0 + (int)ch * 8;
        int h = kbase >> 5;
        const u16* p0 = A + (size_t)grow * 512 + kbase;
        const u16* p1 = A + 1048576 + (size_t)grow * 512 + kbase;
        s16x4 q00 = *(const s16x4*)p0, q01 = *(const s16x4*)(p0 + 4);
        s16x4 q10 = *(const s16x4*)p1, q11 = *(const s16x4*)(p1 + 4);
        const float2* mlp = (const float2*)mlb;
        float2 ma = mlp[(size_t)grow * 16 + h];
        float2 mc = mlp[32768 + (size_t)grow * 16 + h];
        float mx = fmaxf(ma.x, mc.x);
        float w0 = __expf(ma.x - mx), w1 = __expf(mc.x - mx);
        float inv = 1.f / (ma.y * w0 + mc.y * w1);
        bf16x8 ov;
#pragma unroll
        for (int j = 0; j < 4; ++j) {
          ov[j]     = (short)f2bf((bf2f((u16)q00[j]) * w0 + bf2f((u16)q10[j]) * w1) * inv);
          ov[j + 4] = (short)f2bf((bf2f((u16)q01[j]) * w0 + bf2f((u16)q11[j]) * w1) * inv);
        }
        *(bf16x8*)(la + e * 8) = ov;
      } else {
        gload_lds16(A + (size_t)(m0 + row) * K + k0 + ch * 8, la + (e & ~63u) * 8);
      }
    }
#pragma unroll
    for (int r2 = 0; r2 < BN / 32; ++r2) {
      unsigned e = r2 * 256 + tid;
      unsigned row = e >> 3, ch = (e & 7) ^ (row & 7);
      gload_lds16(Bw + (size_t)(n0 + row) * K + k0 + ch * 8, lb + (e & ~63u) * 8);
    }
    __syncthreads();
#pragma unroll
    for (int kk = 0; kk < 2; ++kk) {
      bf16x8 af[FM], bfr[FN];
#pragma unroll
      for (int m = 0; m < FM; ++m) {
        int R = wr * WM + m * 16 + (l & 15);
        int ch = (kk * 4 + (l >> 4)) ^ (R & 7);
        af[m] = *(const bf16x8*)(la + R * 64 + ch * 8);
      }
#pragma unroll
      for (int n = 0; n < FN; ++n) {
        int R = wc * WN + n * 16 + (l & 15);
        int ch = (kk * 4 + (l >> 4)) ^ (R & 7);
        bfr[n] = *(const bf16x8*)(lb + R * 64 + ch * 8);
      }
#pragma unroll
      for (int m = 0; m < FM; ++m)
#pragma unroll
        for (int n = 0; n < FN; ++n)
          acc[m][n] = __builtin_amdgcn_mfma_f32_16x16x32_bf16(af[m], bfr[n], acc[m][n], 0, 0, 0);
    }
  }
  const int rb  = m0 + wr * WM + ((l >> 4) * 4);
  const int cb0 = n0 + wc * WN + (l & 15);
#pragma unroll
  for (int m = 0; m < FM; ++m)
#pragma unroll
    for (int n = 0; n < FN; ++n) {
      int gcol = cb0 + n * 16;
#pragma unroll
      for (int j = 0; j < 4; ++j) {
        int grow = rb + m * 16 + j;
        float v = acc[m][n][j];
        if (MODE == 0) {
          float scv = (gcol < 512) ? qscale : 1.f;
          obf[(size_t)grow * N + gcol] = f2bf(v * scv);
        } else if (MODE == 1 || MODE == 3) {
          of[(size_t)grow * N + gcol] = v + cb[gcol] + add_[(size_t)grow * N + gcol];
        } else {
          float t = v + cb[gcol];
          float ge = 0.5f * t * (1.f + erff(t * 0.70710678118654752f));
          obf[(size_t)grow * N + gcol] = f2bf(ge);
        }
      }
    }
}

template<int MODE, int BM, int BN>
__global__ __launch_bounds__(256) void k_gemm(
    const u16* __restrict__ A, const u16* __restrict__ Bw,
    int M, int N, int K,
    u16* __restrict__ obf, float* __restrict__ of,
    const float* __restrict__ cb, const float* __restrict__ add_,
    float qscale, const float* __restrict__ mlb) {
  gemm_body<MODE, BM, BN>(blockIdx.x, blockIdx.y, A, Bw, M, N, K, obf, of, cb, add_,
                          qscale, mlb);
}

// ---------------- fused pair-bias + flash attention, j-split x2 + r11 prefetch schedule ----------------
// Block = (i-tile 16, b, j-half); grid (64, 2, 2); 8 waves. r15-passing version (session best):
// V-row loads issued right after PF(pfB) (latency drains under both CONSUMEs), ka K-frag loads
// hoisted above the vt transpose writes; pl double-buffered per head; plain (cached) loads.
__global__ __launch_bounds__(512, 2) void k_fab3(const u16* __restrict__ qkv,
    const float* __restrict__ pair, const float* __restrict__ wp,
    u16* __restrict__ opart, float* __restrict__ ml) {
  __shared__ u16 vt[8][64 * 64];     // per-wave V^T [d 64][j 64], swizzled (64 KB)
  __shared__ u16 bt[16][16 * 68];    // bias [h][i*68 + j] (34 KB)
  __shared__ u16 pl[8][2][16 * 64];  // per-wave, per-head P (32 KB)
  const int tid = threadIdx.x, l = tid & 63, w = tid >> 6;
  const int g = l >> 4, ln = l & 15;
  const int i0 = blockIdx.x * 16;
  const int b  = blockIdx.y;
  const int q  = blockIdx.z;
  const int jt0 = q * 8;
  const u16* base = qkv + (size_t)b * 1024 * 1536;
  const f32x4 fz = {0.f, 0.f, 0.f, 0.f};
  // wp B-frags (n = h = ln, k = c = kk*32 + g*8 + e)
  bf16x8 wf[2];
#pragma unroll
  for (int kk = 0; kk < 2; ++kk) {
    const float* wb = wp + ln * 64 + kk * 32 + g * 8;
    float4 w0 = *(const float4*)(wb);
    float4 w1 = *(const float4*)(wb + 4);
    bf16x8 bb;
    bb[0] = (short)f2bf(w0.x); bb[1] = (short)f2bf(w0.y);
    bb[2] = (short)f2bf(w0.z); bb[3] = (short)f2bf(w0.w);
    bb[4] = (short)f2bf(w1.x); bb[5] = (short)f2bf(w1.y);
    bb[6] = (short)f2bf(w1.z); bb[7] = (short)f2bf(w1.w);
    wf[kk] = bb;
  }
  // Q B-frags: lane ln <-> its own row i0+ln (q pre-scaled in QKV GEMM)
  bf16x8 qb[2];
#pragma unroll
  for (int hh = 0; hh < 2; ++hh)
    qb[hh] = *(const bf16x8*)(base + (size_t)(i0 + ln) * 1536 + (w * 2 + hh) * 32 + g * 8);
  float mr[2] = {-1e30f, -1e30f}, ls[2] = {0.f, 0.f};
  f32x4 oa[2][2];
  oa[0][0] = fz; oa[0][1] = fz; oa[1][0] = fz; oa[1][1] = fz;

  auto PF = [&](float4 (&pf)[4][2][2], int ii, int jj0) {
    const float* prow = pair + ((size_t)(b * 1024 + i0 + w * 2 + ii) * 1024 + jj0) * 64;
#pragma unroll
    for (int jf = 0; jf < 4; ++jf)
#pragma unroll
      for (int kk = 0; kk < 2; ++kk) {
        const float* pp = prow + (jf * 16 + ln) * 64 + kk * 32 + g * 8;
        pf[jf][kk][0] = *(const float4*)(pp);
        pf[jf][kk][1] = *(const float4*)(pp + 4);
      }
  };
  auto CONSUME = [&](float4 (&pf)[4][2][2], int ii) {
#pragma unroll
    for (int jf = 0; jf < 4; ++jf) {
      f32x4 ab = fz;
#pragma unroll
      for (int kk = 0; kk < 2; ++kk) {
        float4 p0 = pf[jf][kk][0], p1 = pf[jf][kk][1];
        bf16x8 pk;
        pk[0] = (short)f2bf(p0.x); pk[1] = (short)f2bf(p0.y);
        pk[2] = (short)f2bf(p0.z); pk[3] = (short)f2bf(p0.w);
        pk[4] = (short)f2bf(p1.x); pk[5] = (short)f2bf(p1.y);
        pk[6] = (short)f2bf(p1.z); pk[7] = (short)f2bf(p1.w);
        ab = __builtin_amdgcn_mfma_f32_16x16x32_bf16(pk, wf[kk], ab, 0, 0, 0);
      }
      s16x4 ov;
      ov[0] = (short)f2bf(ab[0]); ov[1] = (short)f2bf(ab[1]);
      ov[2] = (short)f2bf(ab[2]); ov[3] = (short)f2bf(ab[3]);
      *(s16x4*)(&bt[ln][(w * 2 + ii) * 68 + jf * 16 + g * 4]) = ov;
    }
  };

  float4 pfA[4][2][2], pfB[4][2][2];
  PF(pfA, 0, jt0 * 64);                      // prologue: first tile's ii=0
  for (int jt = jt0; jt < jt0 + 8; ++jt) {
    const int j0 = jt * 64;
    __syncthreads();   // all waves done reading bt/vt of previous tile
    PF(pfB, 1, j0);                          // issue ii=1 while consuming ii=0
    // ---- V-row loads issued EARLY (latency drains under both CONSUMEs) ----
    bf16x8 vv[8];
    {
      const u16* vrow = base + (size_t)(j0 + l) * 1536 + 1024 + w * 64;
#pragma unroll
      for (int qd = 0; qd < 8; ++qd) vv[qd] = *(const bf16x8*)(vrow + qd * 8);
    }
    CONSUME(pfA, 0);
    CONSUME(pfB, 1);
    if (jt + 1 < jt0 + 8) PF(pfA, 0, j0 + 64);   // next tile's ii=0 in flight thru phase B
    // ---- ka K-frag loads (L2) hoisted above the vt transpose writes ----
    bf16x8 ka[2][4];
#pragma unroll
    for (int hh = 0; hh < 2; ++hh)
#pragma unroll
      for (int jf = 0; jf < 4; ++jf)
        ka[hh][jf] = *(const bf16x8*)(base + (size_t)(j0 + jf * 16 + ln) * 1536 + 512 +
                                      (w * 2 + hh) * 32 + g * 8);
    // ---- V^T stage (wave's 2 heads = dims w*64..+63), rows j0+l ----
#pragma unroll
    for (int qd = 0; qd < 8; ++qd)
#pragma unroll
      for (int e = 0; e < 8; ++e) {
        int d = qd * 8 + e;
        vt[w][d * 64 + (l ^ ((d & 7) << 3))] = (u16)vv[qd][e];
      }
    __syncthreads();   // bt (cross-wave) + vt visible
    // ---- phase B: per-head flash step ----
#pragma unroll
    for (int hh = 0; hh < 2; ++hh) {
      const int h = w * 2 + hh;
      f32x4 s[4];
#pragma unroll
      for (int jf = 0; jf < 4; ++jf)
        s[jf] = __builtin_amdgcn_mfma_f32_16x16x32_bf16(ka[hh][jf], qb[hh], fz, 0, 0, 0);
#pragma unroll
      for (int jf = 0; jf < 4; ++jf) {
        s16x4 bv = *(const s16x4*)(&bt[h][ln * 68 + jf * 16 + g * 4]);
        s[jf][0] += bf2f((u16)bv[0]);
        s[jf][1] += bf2f((u16)bv[1]);
        s[jf][2] += bf2f((u16)bv[2]);
        s[jf][3] += bf2f((u16)bv[3]);
      }
      float rm = s[0][0];
#pragma unroll
      for (int jf = 0; jf < 4; ++jf)
#pragma unroll
        for (int r = 0; r < 4; ++r) rm = fmaxf(rm, s[jf][r]);
      rm = fmaxf(rm, __shfl_xor(rm, 16));
      rm = fmaxf(rm, __shfl_xor(rm, 32));
      float mn = fmaxf(mr[hh], rm);
      float corr = __expf(mr[hh] - mn);
      float p[4][4];
      float rs = 0.f;
#pragma unroll
      for (int jf = 0; jf < 4; ++jf)
#pragma unroll
        for (int r = 0; r < 4; ++r) { p[jf][r] = __expf(s[jf][r] - mn); rs += p[jf][r]; }
      rs += __shfl_xor(rs, 16);
      rs += __shfl_xor(rs, 32);
      ls[hh] = ls[hh] * corr + rs;
      mr[hh] = mn;
      u16* plw = &pl[w][hh][0];
#pragma unroll
      for (int jf = 0; jf < 4; ++jf) {
        s16x4 pv;
        pv[0] = (short)f2bf(p[jf][0]); pv[1] = (short)f2bf(p[jf][1]);
        pv[2] = (short)f2bf(p[jf][2]); pv[3] = (short)f2bf(p[jf][3]);
        *(s16x4*)(plw + ln * 64 + ((jf * 16 + g * 4) ^ ((ln & 7) << 3))) = pv;
      }
      float cr[4];
#pragma unroll
      for (int r = 0; r < 4; ++r) cr[r] = __shfl(corr, g * 4 + r, 16);
#pragma unroll
      for (int nf = 0; nf < 2; ++nf) {
        oa[hh][nf][0] *= cr[0]; oa[hh][nf][1] *= cr[1];
        oa[hh][nf][2] *= cr[2]; oa[hh][nf][3] *= cr[3];
      }
#pragma unroll
      for (int kk = 0; kk < 2; ++kk) {
        bf16x8 pa = *(const bf16x8*)(plw + ln * 64 + ((kk * 32 + g * 8) ^ ((ln & 7) << 3)));
#pragma unroll
        for (int nf = 0; nf < 2; ++nf) {
          int dp = hh * 32 + nf * 16 + ln;
          bf16x8 vb = *(const bf16x8*)(&vt[w][dp * 64 + ((kk * 32 + g * 8) ^ ((dp & 7) << 3))]);
          oa[hh][nf] = __builtin_amdgcn_mfma_f32_16x16x32_bf16(pa, vb, oa[hh][nf], 0, 0, 0);
        }
      }
    }
  }
  // ---- epilogue: UNNORMALIZED O (bf16) + per-row (m,l); WO GEMM MODE 3 merges ----
  u16* op = opart + (size_t)q * 1048576;
#pragma unroll
  for (int hh = 0; hh < 2; ++hh) {
    const int h = w * 2 + hh;
    if (g == 0) {
      float2* mlp = (float2*)ml;
      mlp[(size_t)q * 32768 + (size_t)(b * 1024 + i0 + ln) * 16 + h] =
          make_float2(mr[hh], ls[hh]);
    }
#pragma unroll
    for (int nf = 0; nf < 2; ++nf)
#pragma unroll
      for (int r = 0; r < 4; ++r) {
        int m = g * 4 + r;
        op[(size_t)(b * 1024 + i0 + m) * 512 + h * 32 + nf * 16 + ln] = f2bf(oa[hh][nf][r]);
      }
  }
}

extern "C" void kernel_launch(void* const* d_in, const int* in_sizes, int n_in,
                              void* d_out, int out_size, void* d_ws, size_t ws_size,
                              hipStream_t stream) {
  const float* x    = (const float*)d_in[0];
  const float* pair = (const float*)d_in[1];
  const float* tc   = (const float*)d_in[2];
  const float* ln1g = (const float*)d_in[3];
  const float* ln1b = (const float*)d_in[4];
  const float* a1w  = (const float*)d_in[5];
  const float* a1b  = (const float*)d_in[6];
  const float* wq   = (const float*)d_in[7];
  const float* wk   = (const float*)d_in[8];
  const float* wv   = (const float*)d_in[9];
  const float* wp   = (const float*)d_in[10];
  const float* wo   = (const float*)d_in[11];
  const float* bo   = (const float*)d_in[12];
  const float* ln2g = (const float*)d_in[13];
  const float* ln2b = (const float*)d_in[14];
  const float* a2w  = (const float*)d_in[15];
  const float* a2b  = (const float*)d_in[16];
  const float* w1   = (const float*)d_in[17];
  const float* b1   = (const float*)d_in[18];
  const float* w2   = (const float*)d_in[19];
  const float* b2   = (const float*)d_in[20];
  float* out = (float*)d_out;

  char* ws = (char*)d_ws;
  size_t off = 0;
  auto alloc = [&](size_t bytes) {
    size_t cur = off;
    off += (bytes + 255) & ~(size_t)255;
    return (void*)(ws + cur);
  };
  float* ss1    = (float*)alloc(2 * 1024 * 4);
  float* ss2    = (float*)alloc(2 * 1024 * 4);
  u16*   qkvw   = (u16*)alloc((size_t)1536 * 512 * 2);
  u16*   wo_bf  = (u16*)alloc((size_t)512 * 512 * 2);
  u16*   w1_bf  = (u16*)alloc((size_t)2048 * 512 * 2);
  u16*   w2_bf  = (u16*)alloc((size_t)512 * 2048 * 2);
  u16*   h_bf   = (u16*)alloc((size_t)2048 * 512 * 2);
  u16*   qkv_bf = (u16*)alloc((size_t)2048 * 1536 * 2);
  u16*   h2_bf  = (u16*)alloc((size_t)2048 * 512 * 2);
  float* xmid   = (float*)alloc((size_t)2048 * 512 * 4);
  u16*   mid_bf = (u16*)alloc((size_t)2048 * 2048 * 2);
  u16*   opart  = (u16*)alloc((size_t)2 * 2048 * 512 * 2);
  float* mlbuf  = (float*)alloc((size_t)2 * 2048 * 16 * 8);
  (void)ws_size; (void)in_sizes; (void)n_in; (void)out_size;

  // weights -> bf16 + adaLN scale/shift, one launch
  k_pre<<<4096, 256, 0, stream>>>(wq, wk, wv, wo, w1, w2,
                                  qkvw, wo_bf, w1_bf, w2_bf,
                                  tc, a1w, a1b, a2w, a2b, ss1, ss2);

  // adaLN1 -> h (bf16)
  k_adaln<<<512, 256, 0, stream>>>(x, ln1g, ln1b, ss1, h_bf);

  // fused QKV GEMM (q pre-scaled by 1/sqrt(32)); 64x128 tiles, 384 blocks
  k_gemm<0, 64, 128><<<dim3(12, 32), 256, 0, stream>>>(h_bf, qkvw, 2048, 1536, 512,
      qkv_bf, nullptr, nullptr, nullptr, 0.17677669529663687f, nullptr);

  // fused pair-bias + flash attention, j-split x2 (pair read once, bias never hits HBM)
  k_fab3<<<dim3(64, 2, 2), 512, 0, stream>>>(qkv_bf, pair, wp, opart, mlbuf);

  // out proj + residual with FUSED flash-partial merge (MODE 3): xmid = x + merge(opart)@wo^T + bo
  k_gemm<3, 64, 64><<<dim3(8, 32), 256, 0, stream>>>(opart, wo_bf, 2048, 512, 512,
      nullptr, xmid, bo, x, 1.f, mlbuf);

  // adaLN2 -> h2 (bf16)
  k_adaln<<<512, 256, 0, stream>>>(xmid, ln2g, ln2b, ss2, h2_bf);

  // FFN1 + exact GELU -> mid (bf16); 64x128 tiles
  k_gemm<2, 64, 128><<<dim3(16, 32), 256, 0, stream>>>(h2_bf, w1_bf, 2048, 2048, 512,
      mid_bf, nullptr, b1, nullptr, 1.f, nullptr);

  // FFN2 + residual -> out (f32); 64x64 tiles
  k_gemm<1, 64, 64><<<dim3(8, 32), 256, 0, stream>>>(mid_bf, w2_bf, 2048, 512, 2048,
      nullptr, out, b2, xmid, 1.f, nullptr);
}